// Round 5
// baseline (324.949 us; speedup 1.0000x reference)
//
#include <hip/hip_runtime.h>
#include <hip/hip_bf16.h>
#include <math.h>

#define B_     16
#define C_     256
#define H_     56
#define W_     56
#define HEADS_ 4
#define CPER_  64
#define R_     16
#define HW_    (H_*W_)      // 3136
#define BN_EPS_ 1e-5f

typedef short bf16x8 __attribute__((ext_vector_type(8)));
typedef float f32x4  __attribute__((ext_vector_type(4)));

__device__ inline unsigned short f2bf(float f) {
    unsigned int u = __builtin_bit_cast(unsigned int, f);
    u += 0x7fffu + ((u >> 16) & 1u);          // RNE (finite inputs only)
    return (unsigned short)(u >> 16);
}

// ---------------- K0: exact fp32 BN+ReLU+mean per (b,c) plane, 4 planes/block ----------
__global__ __launch_bounds__(256) void k_pool(
    const float* __restrict__ x,
    const float* __restrict__ gamma, const float* __restrict__ beta,
    const float* __restrict__ mean,  const float* __restrict__ var,
    float* __restrict__ xavg)
{
    int wv = threadIdx.x >> 6, ln = threadIdx.x & 63;
    int plane = blockIdx.x * 4 + wv;          // b*256 + c
    int c = plane & (C_ - 1);
    float s = gamma[c] * rsqrtf(var[c] + BN_EPS_);
    float t = fmaf(-mean[c], s, beta[c]);
    const float4* xp = (const float4*)(x + (size_t)plane * HW_);
    float sum = 0.f;
    for (int i = ln; i < HW_ / 4; i += 64) {
        float4 v = xp[i];
        sum += fmaxf(fmaf(v.x, s, t), 0.f) + fmaxf(fmaf(v.y, s, t), 0.f)
             + fmaxf(fmaf(v.z, s, t), 0.f) + fmaxf(fmaf(v.w, s, t), 0.f);
    }
    for (int off = 32; off; off >>= 1) sum += __shfl_down(sum, off, 64);
    if (ln == 0) xavg[plane] = sum * (1.f / HW_);
}

// ---------------- K2: SE gate, exact rank-k threshold, compaction, lasso ---------------
__global__ __launch_bounds__(256) void k_se(
    const float* __restrict__ xavg,
    const float* __restrict__ fc1, const float* __restrict__ fc2,
    const float* __restrict__ fc2b, const int* __restrict__ kptr,
    float* __restrict__ maskc, int* __restrict__ aidx64,
    int* __restrict__ act_cnt, float* __restrict__ lasso)
{
    int hb = blockIdx.x;              // h*B + b
    int h = hb / B_, b = hb - h * B_;
    int tid = threadIdx.x;            // = channel c

    __shared__ float sav[C_], sy1[R_], smask[C_], sred[4], sthr;
    __shared__ int scnt, s_ord[C_];

    sav[tid] = xavg[b * C_ + tid];
    if (tid == 0) scnt = 0;
    __syncthreads();

    if (tid < R_) {
        const float* w = fc1 + (size_t)(h * R_ + tid) * C_;
        float acc = 0.f;
        for (int c2 = 0; c2 < C_; ++c2) acc = fmaf(sav[c2], w[c2], acc);
        sy1[tid] = fmaxf(acc, 0.f);
    }
    __syncthreads();

    const float* w2 = fc2 + (size_t)(h * C_ + tid) * R_;
    float acc = fc2b[h * C_ + tid];
    for (int r = 0; r < R_; ++r) acc = fmaf(sy1[r], w2[r], acc);
    float m = fmaxf(acc, 0.f);
    smask[tid] = m;
    __syncthreads();

    float ls = m;
    for (int off = 32; off > 0; off >>= 1) ls += __shfl_down(ls, off, 64);
    int lane = tid & 63, wv = tid >> 6;
    if (lane == 0) sred[wv] = ls;

    int cl = 0, ce = 0;
    for (int j = 0; j < C_; ++j) {
        float vj = smask[j];
        cl += (vj < m);
        ce += (vj == m);
    }
    if (tid == 0) sthr = -1e30f;
    __syncthreads();
    int k = kptr[0];
    if (k > 0 && cl <= k - 1 && (k - 1) < cl + ce) sthr = m;
    __syncthreads();

    float thr = sthr;
    float mc = (m <= thr) ? 0.f : m;
    maskc[hb * C_ + tid] = mc;
    if (mc != 0.f) {
        int p = atomicAdd(&scnt, 1);          // order-free (all consumers use same list)
        s_ord[p] = tid;
    }
    __syncthreads();
    if (tid < 64) aidx64[hb * 64 + tid] = (tid < scnt) ? s_ord[tid] : 0;  // zero-padded
    if (tid == 0) {
        act_cnt[hb] = scnt;
        atomicAdd(lasso, (sred[0] + sred[1] + sred[2] + sred[3]) * (1.f / (B_ * C_)));
    }
}

// ---------------- K2c: compact+mask weights -> Wc[hb][t][j][slot] bf16, PRE-ROTATED ----
// One block per hb. Each thread reads the 9 CONTIGUOUS floats of one (j,cp) weight
// (36B granule -- 9x fewer memory requests than the old per-(t,hb) version whose 4B
// stride-36 reads thrashed L2), stages the rotated bf16 image in LDS, then writes Wc
// fully coalesced. slot = (cp + 8*(j&7)) & 63 pre-rotation kept for k_conv's LDS banks.
__global__ __launch_bounds__(256) void k_wgather(
    const float* __restrict__ convw, const float* __restrict__ maskc,
    const int* __restrict__ aidx64, const int* __restrict__ acnt,
    short* __restrict__ Wc)
{
    int hb = blockIdx.x;
    int h = hb >> 4;
    int tid = threadIdx.x;
    int cnt = acnt[hb];
    __shared__ int s_act[64];
    __shared__ float s_mv[64];
    __shared__ short sO[9 * 4096];            // 73.7 KB staged output
    if (tid < 64) {
        int a = aidx64[hb * 64 + tid];
        s_act[tid] = a;
        s_mv[tid]  = (tid < cnt) ? maskc[hb * C_ + a] : 0.f;
    }
    __syncthreads();
    const float* wsrc = convw + (size_t)h * CPER_ * C_ * 9;
    for (int it = 0; it < 16; ++it) {
        int e = it * 256 + tid;
        int cp = e & 63, j = e >> 6;
        const float* wp = wsrc + ((size_t)j * C_ + s_act[cp]) * 9;
        float mv = s_mv[cp];
        int slot = (cp + 8 * (j & 7)) & 63;
        #pragma unroll
        for (int t = 0; t < 9; ++t)
            sO[t * 4096 + j * 64 + slot] = (short)f2bf(wp[t] * mv);
    }
    __syncthreads();
    short* wdst = Wc + (size_t)hb * 9 * 4096;
    for (int it = 0; it < 18; ++it) {         // 36864 shorts, b128 LDS read + 16B store
        int e = it * 256 + tid;
        *(bf16x8*)&wdst[e * 8] = *(const bf16x8*)&sO[e * 8];
    }
}

// ---------------- K1: BN+ReLU+bf16 DIRECT channel compaction -> xc[hb][px][64] ---------
__global__ __launch_bounds__(256) void k_bnc(
    const float* __restrict__ x,
    const float* __restrict__ gamma, const float* __restrict__ beta,
    const float* __restrict__ mean,  const float* __restrict__ var,
    const int* __restrict__ aidx64, short* __restrict__ xc)
{
    int y = blockIdx.x, b = blockIdx.y;
    int tid = threadIdx.x;                    // tid = h*64 + cp
    int h = tid >> 6;
    __shared__ __align__(16) unsigned short T[W_ * 256];   // [px][h*64+cp], 28.7 KB

    int c = aidx64[(h * B_ + b) * 64 + (tid & 63)];        // padded slots -> c=0 (weights are 0)
    float s = gamma[c] * rsqrtf(var[c] + BN_EPS_);
    float t0 = fmaf(-mean[c], s, beta[c]);
    const float* xrow = x + ((size_t)(b * C_ + c)) * HW_ + y * W_;
    #pragma unroll
    for (int f = 0; f < 14; ++f) {
        float4 v = *(const float4*)(xrow + f * 4);
        int px = f * 4;
        T[(px + 0) * 256 + tid] = f2bf(fmaxf(fmaf(v.x, s, t0), 0.f));
        T[(px + 1) * 256 + tid] = f2bf(fmaxf(fmaf(v.y, s, t0), 0.f));
        T[(px + 2) * 256 + tid] = f2bf(fmaxf(fmaf(v.z, s, t0), 0.f));
        T[(px + 3) * 256 + tid] = f2bf(fmaxf(fmaf(v.w, s, t0), 0.f));
    }
    __syncthreads();

    const uint2* Ts = (const uint2*)T;        // 64 uint2 per pixel row
    uint2* ob = (uint2*)xc;
    #pragma unroll
    for (int it = 0; it < 14; ++it) {
        int e = it * 256 + tid;               // e < 3584 = 56px * 64 uint2
        int px = e >> 6, col4 = e & 63;       // col4 = (h*64+cp)/4
        int hh = col4 >> 4, cp4 = col4 & 15;
        uint2 v = Ts[px * 64 + col4];
        ob[((size_t)(hh * B_ + b) * HW_ + (size_t)y * W_ + px) * 16 + cp4] = v;
    }
}

// ---------------- K3: implicit-GEMM bf16 MFMA conv, 8 waves/block for 4 waves/SIMD -----
// R4 lesson: the manual 2-deep pipeline allocated (VGPR 100) but perf was flat at
// 2 waves/SIMD -- occupancy, not schedule, is the invariant binding k_conv at ~44us.
// Same per-wave code, but 512-thread blocks (8 waves = 8 rows, grid 448): LDS 73.7KB
// still fits 2 blocks/CU -> 16 waves/CU = 4 waves/SIMD (VGPR 100 <= 128 budget of
// __launch_bounds__(512,4)). Staging amortized over 8 rows instead of 4.
__global__ __launch_bounds__(512, 4) void k_conv(
    const short* __restrict__ xc, const short* __restrict__ Wc,
    float* __restrict__ out)
{
    int g = blockIdx.x;
    int vx = g & 7, r = g >> 3;               // XCD-local hb window (Wc/xc L2-resident)
    int hb = vx * 8 + r / 7;                  // 64 hb x 7 bands = 448 blocks
    int band = r - (r / 7) * 7;
    int h = hb >> 4, b = hb & 15;
    int tid = threadIdx.x, lane = tid & 63, wv = tid >> 6;   // wv 0..7
    int m = lane & 15, q = lane >> 4;
    int yrow = band * 8 + wv;
    int arot = q * 8 + 8 * (m & 7);           // A-frag slot rotation (add c0, &63)

    __shared__ short sW[9 * 4096];            // 73.7 KB, all taps

    const short* Wh = Wc + (size_t)hb * 9 * 4096;
    const short* xb = xc + (size_t)hb * HW_ * 64 + q * 8;   // q*8 folded into base

    bf16x8 bFb[3][4];                         // B rotating buffer (48 VGPR)
    bf16x8 aFb[2][4];                         // A rotating buffer (32 VGPR)

#define LOADB_(kk) { \
        const int t_ = (kk) >> 1, c0_ = ((kk) & 1) * 32; \
        const int dy_ = t_ / 3 - 1, dx_ = t_ % 3 - 1; \
        int gy_ = yrow + dy_; \
        bool ok_ = (unsigned)gy_ < (unsigned)H_; \
        _Pragma("unroll") \
        for (int xt_ = 0; xt_ < 4; ++xt_) { \
            int gx_ = xt_ * 16 + m + dx_; \
            bf16x8 v_ = {0, 0, 0, 0, 0, 0, 0, 0}; \
            if (ok_ && (unsigned)gx_ < (unsigned)W_) \
                v_ = *(const bf16x8*)(xb + ((size_t)(gy_ * W_ + gx_)) * 64 + c0_); \
            bFb[(kk) % 3][xt_] = v_; \
        } }

#define LOADA_(kk) { \
        const int t_ = (kk) >> 1, c0_ = ((kk) & 1) * 32; \
        const short* sWc_ = sW + t_ * 4096; \
        _Pragma("unroll") \
        for (int jt_ = 0; jt_ < 4; ++jt_) \
            aFb[(kk) % 2][jt_] = *(const bf16x8*)&sWc_[(jt_ * 16 + m) * 64 + ((c0_ + arot) & 63)]; \
        }

    LOADB_(0);                                // hide under staging + barrier
    LOADB_(1);

    #pragma unroll
    for (int it = 0; it < 9; ++it) {          // stage all 9 taps, 16B/lane coalesced
        int e = it * 512 + tid;
        *(bf16x8*)&sW[e * 8] = *(const bf16x8*)(Wh + e * 8);
    }
    __syncthreads();

    f32x4 acc[4][4];                          // [jt][xt], 64 AGPR
    #pragma unroll
    for (int i = 0; i < 4; ++i)
        #pragma unroll
        for (int j = 0; j < 4; ++j)
            #pragma unroll
            for (int rr = 0; rr < 4; ++rr) acc[i][j][rr] = 0.f;

    LOADA_(0);

    #pragma unroll
    for (int k = 0; k < 18; ++k) {            // 18 clusters = 9 taps x 2 c0-halves
        if (k + 2 < 18) LOADB_(k + 2);        // issue 2 clusters ahead (WAR-pinned)
        if (k + 1 < 18) LOADA_(k + 1);        // LDS prefetch 1 cluster ahead
        #pragma unroll
        for (int jt = 0; jt < 4; ++jt)
            #pragma unroll
            for (int xt = 0; xt < 4; ++xt)
                acc[jt][xt] = __builtin_amdgcn_mfma_f32_16x16x32_bf16(
                    aFb[k % 2][jt], bFb[k % 3][xt], acc[jt][xt], 0, 0, 0);
    }
#undef LOADB_
#undef LOADA_

    #pragma unroll
    for (int xt = 0; xt < 4; ++xt) {
        int xx = xt * 16 + m;
        if (xx < W_) {
            #pragma unroll
            for (int jt = 0; jt < 4; ++jt)
                #pragma unroll
                for (int rr = 0; rr < 4; ++rr) {
                    int j = jt * 16 + q * 4 + rr;         // D: row = quad*4 + reg
                    int oc = j * HEADS_ + h;              // head interleave
                    out[(((size_t)b * C_ + oc) * H_ + yrow) * W_ + xx] = acc[jt][xt][rr];
                }
        }
    }
}

// ---------------- launch ----------------------------------------------------------------
extern "C" void kernel_launch(void* const* d_in, const int* in_sizes, int n_in,
                              void* d_out, int out_size, void* d_ws, size_t ws_size,
                              hipStream_t stream)
{
    const float* x     = (const float*)d_in[0];
    const float* gamma = (const float*)d_in[1];
    const float* beta  = (const float*)d_in[2];
    const float* mean  = (const float*)d_in[3];
    const float* var   = (const float*)d_in[4];
    const float* fc1   = (const float*)d_in[5];
    const float* fc2   = (const float*)d_in[6];
    const float* fc2b  = (const float*)d_in[7];
    const float* convw = (const float*)d_in[8];
    const int*   kptr  = (const int*)d_in[9];

    float* out   = (float*)d_out;
    float* lasso = out + (size_t)B_ * C_ * HW_;

    char* ws = (char*)d_ws;
    size_t off = 0;
    short* xc    = (short*)(ws + off); off += (size_t)HEADS_ * B_ * HW_ * 64 * 2;  // 25.7 MB
    off = (off + 255) & ~(size_t)255;
    float* xavg  = (float*)(ws + off); off += (size_t)B_ * C_ * 4;
    float* maskc = (float*)(ws + off); off += (size_t)HEADS_ * B_ * C_ * 4;
    int*   aidx64= (int*)  (ws + off); off += (size_t)HEADS_ * B_ * 64 * 4;
    int*   acnt  = (int*)  (ws + off); off += (size_t)HEADS_ * B_ * 4;
    off = (off + 255) & ~(size_t)255;
    short* Wc    = (short*)(ws + off); off += (size_t)HEADS_ * B_ * 9 * CPER_ * 64 * 2; // 4.72 MB

    hipMemsetAsync(lasso, 0, 4, stream);

    k_pool<<<B_ * C_ / 4, 256, 0, stream>>>(x, gamma, beta, mean, var, xavg);
    k_se<<<HEADS_ * B_, 256, 0, stream>>>(xavg, fc1, fc2, fc2b, kptr,
                                          maskc, aidx64, acnt, lasso);
    k_wgather<<<HEADS_ * B_, 256, 0, stream>>>(convw, maskc, aidx64, acnt, Wc);
    k_bnc<<<dim3(H_, B_), 256, 0, stream>>>(x, gamma, beta, mean, var, aidx64, xc);
    k_conv<<<HEADS_ * B_ * (H_ / 8), 512, 0, stream>>>(xc, Wc, out);
}

// Round 6
// 195.615 us; speedup vs baseline: 1.6612x; 1.6612x over previous
//
#include <hip/hip_runtime.h>
#include <hip/hip_bf16.h>
#include <math.h>

#define B_     16
#define C_     256
#define H_     56
#define W_     56
#define HEADS_ 4
#define CPER_  64
#define R_     16
#define HW_    (H_*W_)      // 3136
#define BN_EPS_ 1e-5f

typedef short bf16x8 __attribute__((ext_vector_type(8)));
typedef float f32x4  __attribute__((ext_vector_type(4)));

__device__ inline unsigned short f2bf(float f) {
    unsigned int u = __builtin_bit_cast(unsigned int, f);
    u += 0x7fffu + ((u >> 16) & 1u);          // RNE (finite inputs only)
    return (unsigned short)(u >> 16);
}

// ---------------- K0: exact fp32 BN+ReLU+mean per (b,c) plane, 4 planes/block ----------
__global__ __launch_bounds__(256) void k_pool(
    const float* __restrict__ x,
    const float* __restrict__ gamma, const float* __restrict__ beta,
    const float* __restrict__ mean,  const float* __restrict__ var,
    float* __restrict__ xavg)
{
    int wv = threadIdx.x >> 6, ln = threadIdx.x & 63;
    int plane = blockIdx.x * 4 + wv;          // b*256 + c
    int c = plane & (C_ - 1);
    float s = gamma[c] * rsqrtf(var[c] + BN_EPS_);
    float t = fmaf(-mean[c], s, beta[c]);
    const float4* xp = (const float4*)(x + (size_t)plane * HW_);
    float sum = 0.f;
    for (int i = ln; i < HW_ / 4; i += 64) {
        float4 v = xp[i];
        sum += fmaxf(fmaf(v.x, s, t), 0.f) + fmaxf(fmaf(v.y, s, t), 0.f)
             + fmaxf(fmaf(v.z, s, t), 0.f) + fmaxf(fmaf(v.w, s, t), 0.f);
    }
    for (int off = 32; off; off >>= 1) sum += __shfl_down(sum, off, 64);
    if (ln == 0) xavg[plane] = sum * (1.f / HW_);
}

// ---------------- K2: SE gate, exact rank-k threshold, compaction, lasso ---------------
__global__ __launch_bounds__(256) void k_se(
    const float* __restrict__ xavg,
    const float* __restrict__ fc1, const float* __restrict__ fc2,
    const float* __restrict__ fc2b, const int* __restrict__ kptr,
    float* __restrict__ maskc, int* __restrict__ aidx64,
    int* __restrict__ act_cnt, float* __restrict__ lasso)
{
    int hb = blockIdx.x;              // h*B + b
    int h = hb / B_, b = hb - h * B_;
    int tid = threadIdx.x;            // = channel c

    __shared__ float sav[C_], sy1[R_], smask[C_], sred[4], sthr;
    __shared__ int scnt, s_ord[C_];

    sav[tid] = xavg[b * C_ + tid];
    if (tid == 0) scnt = 0;
    __syncthreads();

    if (tid < R_) {
        const float* w = fc1 + (size_t)(h * R_ + tid) * C_;
        float acc = 0.f;
        for (int c2 = 0; c2 < C_; ++c2) acc = fmaf(sav[c2], w[c2], acc);
        sy1[tid] = fmaxf(acc, 0.f);
    }
    __syncthreads();

    const float* w2 = fc2 + (size_t)(h * C_ + tid) * R_;
    float acc = fc2b[h * C_ + tid];
    for (int r = 0; r < R_; ++r) acc = fmaf(sy1[r], w2[r], acc);
    float m = fmaxf(acc, 0.f);
    smask[tid] = m;
    __syncthreads();

    float ls = m;
    for (int off = 32; off > 0; off >>= 1) ls += __shfl_down(ls, off, 64);
    int lane = tid & 63, wv = tid >> 6;
    if (lane == 0) sred[wv] = ls;

    int cl = 0, ce = 0;
    for (int j = 0; j < C_; ++j) {
        float vj = smask[j];
        cl += (vj < m);
        ce += (vj == m);
    }
    if (tid == 0) sthr = -1e30f;
    __syncthreads();
    int k = kptr[0];
    if (k > 0 && cl <= k - 1 && (k - 1) < cl + ce) sthr = m;
    __syncthreads();

    float thr = sthr;
    float mc = (m <= thr) ? 0.f : m;
    maskc[hb * C_ + tid] = mc;
    if (mc != 0.f) {
        int p = atomicAdd(&scnt, 1);          // order-free (all consumers use same list)
        s_ord[p] = tid;
    }
    __syncthreads();
    if (tid < 64) aidx64[hb * 64 + tid] = (tid < scnt) ? s_ord[tid] : 0;  // zero-padded
    if (tid == 0) {
        act_cnt[hb] = scnt;
        atomicAdd(lasso, (sred[0] + sred[1] + sred[2] + sred[3]) * (1.f / (B_ * C_)));
    }
}

// ---------------- K2c: compact+mask weights -> Wc[hb][t][j][slot] bf16, PRE-ROTATED ----
// One block per hb. Each thread reads the 9 CONTIGUOUS floats of one (j,cp) weight
// (36B granule), stages the rotated bf16 image in LDS, then writes Wc fully coalesced.
__global__ __launch_bounds__(256) void k_wgather(
    const float* __restrict__ convw, const float* __restrict__ maskc,
    const int* __restrict__ aidx64, const int* __restrict__ acnt,
    short* __restrict__ Wc)
{
    int hb = blockIdx.x;
    int h = hb >> 4;
    int tid = threadIdx.x;
    int cnt = acnt[hb];
    __shared__ int s_act[64];
    __shared__ float s_mv[64];
    __shared__ short sO[9 * 4096];            // 73.7 KB staged output
    if (tid < 64) {
        int a = aidx64[hb * 64 + tid];
        s_act[tid] = a;
        s_mv[tid]  = (tid < cnt) ? maskc[hb * C_ + a] : 0.f;
    }
    __syncthreads();
    const float* wsrc = convw + (size_t)h * CPER_ * C_ * 9;
    for (int it = 0; it < 16; ++it) {
        int e = it * 256 + tid;
        int cp = e & 63, j = e >> 6;
        const float* wp = wsrc + ((size_t)j * C_ + s_act[cp]) * 9;
        float mv = s_mv[cp];
        int slot = (cp + 8 * (j & 7)) & 63;
        #pragma unroll
        for (int t = 0; t < 9; ++t)
            sO[t * 4096 + j * 64 + slot] = (short)f2bf(wp[t] * mv);
    }
    __syncthreads();
    short* wdst = Wc + (size_t)hb * 9 * 4096;
    for (int it = 0; it < 18; ++it) {         // 36864 shorts, b128 LDS read + 16B store
        int e = it * 256 + tid;
        *(bf16x8*)&wdst[e * 8] = *(const bf16x8*)&sO[e * 8];
    }
}

// ---------------- K1: BN+ReLU+bf16 DIRECT channel compaction -> xc[hb][px][64] ---------
__global__ __launch_bounds__(256) void k_bnc(
    const float* __restrict__ x,
    const float* __restrict__ gamma, const float* __restrict__ beta,
    const float* __restrict__ mean,  const float* __restrict__ var,
    const int* __restrict__ aidx64, short* __restrict__ xc)
{
    int y = blockIdx.x, b = blockIdx.y;
    int tid = threadIdx.x;                    // tid = h*64 + cp
    int h = tid >> 6;
    __shared__ __align__(16) unsigned short T[W_ * 256];   // [px][h*64+cp], 28.7 KB

    int c = aidx64[(h * B_ + b) * 64 + (tid & 63)];        // padded slots -> c=0 (weights are 0)
    float s = gamma[c] * rsqrtf(var[c] + BN_EPS_);
    float t0 = fmaf(-mean[c], s, beta[c]);
    const float* xrow = x + ((size_t)(b * C_ + c)) * HW_ + y * W_;
    #pragma unroll
    for (int f = 0; f < 14; ++f) {
        float4 v = *(const float4*)(xrow + f * 4);
        int px = f * 4;
        T[(px + 0) * 256 + tid] = f2bf(fmaxf(fmaf(v.x, s, t0), 0.f));
        T[(px + 1) * 256 + tid] = f2bf(fmaxf(fmaf(v.y, s, t0), 0.f));
        T[(px + 2) * 256 + tid] = f2bf(fmaxf(fmaf(v.z, s, t0), 0.f));
        T[(px + 3) * 256 + tid] = f2bf(fmaxf(fmaf(v.w, s, t0), 0.f));
    }
    __syncthreads();

    const uint2* Ts = (const uint2*)T;        // 64 uint2 per pixel row
    uint2* ob = (uint2*)xc;
    #pragma unroll
    for (int it = 0; it < 14; ++it) {
        int e = it * 256 + tid;               // e < 3584 = 56px * 64 uint2
        int px = e >> 6, col4 = e & 63;       // col4 = (h*64+cp)/4
        int hh = col4 >> 4, cp4 = col4 & 15;
        uint2 v = Ts[px * 64 + col4];
        ob[((size_t)(hh * B_ + b) * HW_ + (size_t)y * W_ + px) * 16 + cp4] = v;
    }
}

// ---------------- K3: implicit-GEMM bf16 MFMA conv, 8 waves/block, UNCAPPED regs -------
// R5 lesson: __launch_bounds__(512,4) capped the register budget -> rotating buffers
// spilled to scratch (VGPR=64, 725MB of FETCH+WRITE, 171us). The occupancy experiment
// was sabotaged, not falsified. This round: (512,2) -> no effective register cap
// (budget ~1024/wave); the 73.7KB LDS is what limits residency to 2 blocks/CU
// = 16 waves/CU = 4 waves/SIMD (vs 2 in R4). Grid 448 <= capacity 512 -> ALL blocks
// co-resident, zero tail rounds. Per-wave code identical to the R4-verified pipeline.
__global__ __launch_bounds__(512, 2) void k_conv(
    const short* __restrict__ xc, const short* __restrict__ Wc,
    float* __restrict__ out)
{
    int g = blockIdx.x;
    int vx = g & 7, r = g >> 3;               // XCD-local hb window (Wc/xc L2-resident)
    int hb = vx * 8 + r / 7;                  // 64 hb x 7 bands = 448 blocks
    int band = r - (r / 7) * 7;
    int h = hb >> 4, b = hb & 15;
    int tid = threadIdx.x, lane = tid & 63, wv = tid >> 6;   // wv 0..7
    int m = lane & 15, q = lane >> 4;
    int yrow = band * 8 + wv;
    int arot = q * 8 + 8 * (m & 7);           // A-frag slot rotation (add c0, &63)

    __shared__ short sW[9 * 4096];            // 73.7 KB, all taps

    const short* Wh = Wc + (size_t)hb * 9 * 4096;
    const short* xb = xc + (size_t)hb * HW_ * 64 + q * 8;   // q*8 folded into base

    bf16x8 bFb[3][4];                         // B rotating buffer (48 VGPR)
    bf16x8 aFb[2][4];                         // A rotating buffer (32 VGPR)

#define LOADB_(kk) { \
        const int t_ = (kk) >> 1, c0_ = ((kk) & 1) * 32; \
        const int dy_ = t_ / 3 - 1, dx_ = t_ % 3 - 1; \
        int gy_ = yrow + dy_; \
        bool ok_ = (unsigned)gy_ < (unsigned)H_; \
        _Pragma("unroll") \
        for (int xt_ = 0; xt_ < 4; ++xt_) { \
            int gx_ = xt_ * 16 + m + dx_; \
            bf16x8 v_ = {0, 0, 0, 0, 0, 0, 0, 0}; \
            if (ok_ && (unsigned)gx_ < (unsigned)W_) \
                v_ = *(const bf16x8*)(xb + ((size_t)(gy_ * W_ + gx_)) * 64 + c0_); \
            bFb[(kk) % 3][xt_] = v_; \
        } }

#define LOADA_(kk) { \
        const int t_ = (kk) >> 1, c0_ = ((kk) & 1) * 32; \
        const short* sWc_ = sW + t_ * 4096; \
        _Pragma("unroll") \
        for (int jt_ = 0; jt_ < 4; ++jt_) \
            aFb[(kk) % 2][jt_] = *(const bf16x8*)&sWc_[(jt_ * 16 + m) * 64 + ((c0_ + arot) & 63)]; \
        }

    LOADB_(0);                                // hide under staging + barrier
    LOADB_(1);

    #pragma unroll
    for (int it = 0; it < 9; ++it) {          // stage all 9 taps, 16B/lane coalesced
        int e = it * 512 + tid;
        *(bf16x8*)&sW[e * 8] = *(const bf16x8*)(Wh + e * 8);
    }
    __syncthreads();

    f32x4 acc[4][4];                          // [jt][xt], 64 AGPR
    #pragma unroll
    for (int i = 0; i < 4; ++i)
        #pragma unroll
        for (int j = 0; j < 4; ++j)
            #pragma unroll
            for (int rr = 0; rr < 4; ++rr) acc[i][j][rr] = 0.f;

    LOADA_(0);

    #pragma unroll
    for (int k = 0; k < 18; ++k) {            // 18 clusters = 9 taps x 2 c0-halves
        if (k + 2 < 18) LOADB_(k + 2);        // issue 2 clusters ahead (WAR-pinned)
        if (k + 1 < 18) LOADA_(k + 1);        // LDS prefetch 1 cluster ahead
        #pragma unroll
        for (int jt = 0; jt < 4; ++jt)
            #pragma unroll
            for (int xt = 0; xt < 4; ++xt)
                acc[jt][xt] = __builtin_amdgcn_mfma_f32_16x16x32_bf16(
                    aFb[k % 2][jt], bFb[k % 3][xt], acc[jt][xt], 0, 0, 0);
    }
#undef LOADB_
#undef LOADA_

    #pragma unroll
    for (int xt = 0; xt < 4; ++xt) {
        int xx = xt * 16 + m;
        if (xx < W_) {
            #pragma unroll
            for (int jt = 0; jt < 4; ++jt)
                #pragma unroll
                for (int rr = 0; rr < 4; ++rr) {
                    int j = jt * 16 + q * 4 + rr;         // D: row = quad*4 + reg
                    int oc = j * HEADS_ + h;              // head interleave
                    out[(((size_t)b * C_ + oc) * H_ + yrow) * W_ + xx] = acc[jt][xt][rr];
                }
        }
    }
}

// ---------------- launch ----------------------------------------------------------------
extern "C" void kernel_launch(void* const* d_in, const int* in_sizes, int n_in,
                              void* d_out, int out_size, void* d_ws, size_t ws_size,
                              hipStream_t stream)
{
    const float* x     = (const float*)d_in[0];
    const float* gamma = (const float*)d_in[1];
    const float* beta  = (const float*)d_in[2];
    const float* mean  = (const float*)d_in[3];
    const float* var   = (const float*)d_in[4];
    const float* fc1   = (const float*)d_in[5];
    const float* fc2   = (const float*)d_in[6];
    const float* fc2b  = (const float*)d_in[7];
    const float* convw = (const float*)d_in[8];
    const int*   kptr  = (const int*)d_in[9];

    float* out   = (float*)d_out;
    float* lasso = out + (size_t)B_ * C_ * HW_;

    char* ws = (char*)d_ws;
    size_t off = 0;
    short* xc    = (short*)(ws + off); off += (size_t)HEADS_ * B_ * HW_ * 64 * 2;  // 25.7 MB
    off = (off + 255) & ~(size_t)255;
    float* xavg  = (float*)(ws + off); off += (size_t)B_ * C_ * 4;
    float* maskc = (float*)(ws + off); off += (size_t)HEADS_ * B_ * C_ * 4;
    int*   aidx64= (int*)  (ws + off); off += (size_t)HEADS_ * B_ * 64 * 4;
    int*   acnt  = (int*)  (ws + off); off += (size_t)HEADS_ * B_ * 4;
    off = (off + 255) & ~(size_t)255;
    short* Wc    = (short*)(ws + off); off += (size_t)HEADS_ * B_ * 9 * CPER_ * 64 * 2; // 4.72 MB

    hipMemsetAsync(lasso, 0, 4, stream);

    k_pool<<<B_ * C_ / 4, 256, 0, stream>>>(x, gamma, beta, mean, var, xavg);
    k_se<<<HEADS_ * B_, 256, 0, stream>>>(xavg, fc1, fc2, fc2b, kptr,
                                          maskc, aidx64, acnt, lasso);
    k_wgather<<<HEADS_ * B_, 256, 0, stream>>>(convw, maskc, aidx64, acnt, Wc);
    k_bnc<<<dim3(H_, B_), 256, 0, stream>>>(x, gamma, beta, mean, var, aidx64, xc);
    k_conv<<<HEADS_ * B_ * (H_ / 8), 512, 0, stream>>>(xc, Wc, out);
}

// Round 7
// 193.610 us; speedup vs baseline: 1.6784x; 1.0104x over previous
//
#include <hip/hip_runtime.h>
#include <hip/hip_bf16.h>
#include <math.h>

#define B_     16
#define C_     256
#define H_     56
#define W_     56
#define HEADS_ 4
#define CPER_  64
#define R_     16
#define HW_    (H_*W_)      // 3136
#define BN_EPS_ 1e-5f

typedef short bf16x8 __attribute__((ext_vector_type(8)));
typedef float f32x4  __attribute__((ext_vector_type(4)));

__device__ inline unsigned short f2bf(float f) {
    unsigned int u = __builtin_bit_cast(unsigned int, f);
    u += 0x7fffu + ((u >> 16) & 1u);          // RNE (finite inputs only)
    return (unsigned short)(u >> 16);
}

// ---------------- K0: exact fp32 BN+ReLU+mean per (b,c) plane, 4 planes/block ----------
__global__ __launch_bounds__(256) void k_pool(
    const float* __restrict__ x,
    const float* __restrict__ gamma, const float* __restrict__ beta,
    const float* __restrict__ mean,  const float* __restrict__ var,
    float* __restrict__ xavg)
{
    int wv = threadIdx.x >> 6, ln = threadIdx.x & 63;
    int plane = blockIdx.x * 4 + wv;          // b*256 + c
    int c = plane & (C_ - 1);
    float s = gamma[c] * rsqrtf(var[c] + BN_EPS_);
    float t = fmaf(-mean[c], s, beta[c]);
    const float4* xp = (const float4*)(x + (size_t)plane * HW_);
    float sum = 0.f;
    for (int i = ln; i < HW_ / 4; i += 64) {
        float4 v = xp[i];
        sum += fmaxf(fmaf(v.x, s, t), 0.f) + fmaxf(fmaf(v.y, s, t), 0.f)
             + fmaxf(fmaf(v.z, s, t), 0.f) + fmaxf(fmaf(v.w, s, t), 0.f);
    }
    for (int off = 32; off; off >>= 1) sum += __shfl_down(sum, off, 64);
    if (ln == 0) xavg[plane] = sum * (1.f / HW_);
}

// ---------------- K2: SE gate + threshold + compaction + lasso + WEIGHT GATHER ---------
// k_se and k_wgather had identical hb-grids: fused. Mask values and the active list
// never leave LDS; saves one launch and the maskc global round-trip.
__global__ __launch_bounds__(256) void k_se_wg(
    const float* __restrict__ xavg,
    const float* __restrict__ fc1, const float* __restrict__ fc2,
    const float* __restrict__ fc2b, const int* __restrict__ kptr,
    const float* __restrict__ convw,
    int* __restrict__ aidx64, float* __restrict__ lasso,
    short* __restrict__ Wc)
{
    int hb = blockIdx.x;              // h*B + b
    int h = hb / B_, b = hb - h * B_;
    int tid = threadIdx.x;            // = channel c

    __shared__ float sav[C_], sy1[R_], smask[C_], sred[4], sthr;
    __shared__ int scnt, s_ord[C_];
    __shared__ int s_act[64];
    __shared__ float s_mv[64];
    __shared__ short sO[9 * 4096];    // 73.7 KB staged weight output

    sav[tid] = xavg[b * C_ + tid];
    if (tid == 0) scnt = 0;
    __syncthreads();

    if (tid < R_) {
        const float* w = fc1 + (size_t)(h * R_ + tid) * C_;
        float acc = 0.f;
        for (int c2 = 0; c2 < C_; ++c2) acc = fmaf(sav[c2], w[c2], acc);
        sy1[tid] = fmaxf(acc, 0.f);
    }
    __syncthreads();

    const float* w2 = fc2 + (size_t)(h * C_ + tid) * R_;
    float acc = fc2b[h * C_ + tid];
    for (int r = 0; r < R_; ++r) acc = fmaf(sy1[r], w2[r], acc);
    float m = fmaxf(acc, 0.f);
    smask[tid] = m;
    __syncthreads();

    float ls = m;
    for (int off = 32; off > 0; off >>= 1) ls += __shfl_down(ls, off, 64);
    int lane = tid & 63, wv = tid >> 6;
    if (lane == 0) sred[wv] = ls;

    int cl = 0, ce = 0;
    for (int j = 0; j < C_; ++j) {
        float vj = smask[j];
        cl += (vj < m);
        ce += (vj == m);
    }
    if (tid == 0) sthr = -1e30f;
    __syncthreads();
    int k = kptr[0];
    if (k > 0 && cl <= k - 1 && (k - 1) < cl + ce) sthr = m;
    __syncthreads();

    float thr = sthr;
    float mc = (m <= thr) ? 0.f : m;
    if (mc != 0.f) {
        int p = atomicAdd(&scnt, 1);          // order-free (all consumers use same list)
        s_ord[p] = tid;
    }
    __syncthreads();
    if (tid < 64) {
        int a = (tid < scnt) ? s_ord[tid] : 0;  // zero-padded
        aidx64[hb * 64 + tid] = a;
        s_act[tid] = a;
        s_mv[tid]  = (tid < scnt) ? smask[a] : 0.f;
    }
    if (tid == 0)
        atomicAdd(lasso, (sred[0] + sred[1] + sred[2] + sred[3]) * (1.f / (B_ * C_)));
    __syncthreads();

    // ---- weight gather: 36B-granule reads, rotated bf16 stage, coalesced write -------
    const float* wsrc = convw + (size_t)h * CPER_ * C_ * 9;
    for (int it = 0; it < 16; ++it) {
        int e = it * 256 + tid;
        int cp = e & 63, j = e >> 6;
        const float* wp = wsrc + ((size_t)j * C_ + s_act[cp]) * 9;
        float mv = s_mv[cp];
        int slot = (cp + 8 * (j & 7)) & 63;   // pre-rotate for k_conv LDS bank spread
        #pragma unroll
        for (int t = 0; t < 9; ++t)
            sO[t * 4096 + j * 64 + slot] = (short)f2bf(wp[t] * mv);
    }
    __syncthreads();
    short* wdst = Wc + (size_t)hb * 9 * 4096;
    for (int it = 0; it < 18; ++it) {
        int e = it * 256 + tid;
        *(bf16x8*)&wdst[e * 8] = *(const bf16x8*)&sO[e * 8];
    }
}

// ---------------- K1: BN+ReLU+bf16 DIRECT channel compaction -> xc[hb][px][64] ---------
__global__ __launch_bounds__(256) void k_bnc(
    const float* __restrict__ x,
    const float* __restrict__ gamma, const float* __restrict__ beta,
    const float* __restrict__ mean,  const float* __restrict__ var,
    const int* __restrict__ aidx64, short* __restrict__ xc)
{
    int y = blockIdx.x, b = blockIdx.y;
    int tid = threadIdx.x;                    // tid = h*64 + cp
    int h = tid >> 6;
    __shared__ __align__(16) unsigned short T[W_ * 256];   // [px][h*64+cp], 28.7 KB

    int c = aidx64[(h * B_ + b) * 64 + (tid & 63)];        // padded slots -> c=0 (weights are 0)
    float s = gamma[c] * rsqrtf(var[c] + BN_EPS_);
    float t0 = fmaf(-mean[c], s, beta[c]);
    const float* xrow = x + ((size_t)(b * C_ + c)) * HW_ + y * W_;
    #pragma unroll
    for (int f = 0; f < 14; ++f) {
        float4 v = *(const float4*)(xrow + f * 4);
        int px = f * 4;
        T[(px + 0) * 256 + tid] = f2bf(fmaxf(fmaf(v.x, s, t0), 0.f));
        T[(px + 1) * 256 + tid] = f2bf(fmaxf(fmaf(v.y, s, t0), 0.f));
        T[(px + 2) * 256 + tid] = f2bf(fmaxf(fmaf(v.z, s, t0), 0.f));
        T[(px + 3) * 256 + tid] = f2bf(fmaxf(fmaf(v.w, s, t0), 0.f));
    }
    __syncthreads();

    const uint2* Ts = (const uint2*)T;        // 64 uint2 per pixel row
    uint2* ob = (uint2*)xc;
    #pragma unroll
    for (int it = 0; it < 14; ++it) {
        int e = it * 256 + tid;               // e < 3584 = 56px * 64 uint2
        int px = e >> 6, col4 = e & 63;       // col4 = (h*64+cp)/4
        int hh = col4 >> 4, cp4 = col4 & 15;
        uint2 v = Ts[px * 64 + col4];
        ob[((size_t)(hh * B_ + b) * HW_ + (size_t)y * W_ + px) * 16 + cp4] = v;
    }
}

// ---------------- K3: implicit-GEMM conv, 64ch x 32px wave tile, TRUE 4 waves/SIMD -----
// R6 lesson: gfx950's unified VGPR+AGPR file means VGPR_Count(100) + acc AGPRs(64) =
// 164/wave -> only 2 waves/SIMD ever ran in R0-R6. This version shrinks the wave tile
// to 64ch x 32px: acc 32 AGPR + bFb[4][2] 32 VGPR (3-deep B pipeline) + aFb[2][4] 32
// VGPR + addressing ~= <=128 total -> 2 blocks/CU x 8 waves = 4 waves/SIMD for real.
// Block = 8 rows x one x-half; grid 896; same-hb blocks share an XCD (L2-resident).
__global__ __launch_bounds__(512, 2) void k_conv(
    const short* __restrict__ xc, const short* __restrict__ Wc,
    float* __restrict__ out)
{
    int g = blockIdx.x;
    int vx = g & 7, r = g >> 3;               // r in [0,112)
    int hb = vx * 8 + r / 14;                 // 14 blocks per hb, one XCD
    int sub = r - (r / 14) * 14;              // 0..13
    int band = sub >> 1, xh = sub & 1;
    int h = hb >> 4, b = hb & 15;
    int tid = threadIdx.x, lane = tid & 63, wv = tid >> 6;   // wv 0..7 = row
    int m = lane & 15, q = lane >> 4;
    int yrow = band * 8 + wv;
    int xbase = xh * 32;
    int arot = q * 8 + 8 * (m & 7);           // A-frag slot rotation (add c0, &63)

    __shared__ short sW[9 * 4096];            // 73.7 KB, all taps

    const short* Wh = Wc + (size_t)hb * 9 * 4096;
    const short* xb = xc + (size_t)hb * HW_ * 64 + q * 8;   // q*8 folded into base

    bf16x8 bFb[4][2];                         // B rotating buffer, 3-deep (32 VGPR)
    bf16x8 aFb[2][4];                         // A rotating buffer (32 VGPR)

#define LOADB_(kk) { \
        const int t_ = (kk) >> 1, c0_ = ((kk) & 1) * 32; \
        const int dy_ = t_ / 3 - 1, dx_ = t_ % 3 - 1; \
        int gy_ = yrow + dy_; \
        bool ok_ = (unsigned)gy_ < (unsigned)H_; \
        _Pragma("unroll") \
        for (int xt_ = 0; xt_ < 2; ++xt_) { \
            int gx_ = xbase + xt_ * 16 + m + dx_; \
            bf16x8 v_ = {0, 0, 0, 0, 0, 0, 0, 0}; \
            if (ok_ && (unsigned)gx_ < (unsigned)W_) \
                v_ = *(const bf16x8*)(xb + ((size_t)(gy_ * W_ + gx_)) * 64 + c0_); \
            bFb[(kk) & 3][xt_] = v_; \
        } }

#define LOADA_(kk) { \
        const int t_ = (kk) >> 1, c0_ = ((kk) & 1) * 32; \
        const short* sWc_ = sW + t_ * 4096; \
        _Pragma("unroll") \
        for (int jt_ = 0; jt_ < 4; ++jt_) \
            aFb[(kk) & 1][jt_] = *(const bf16x8*)&sWc_[(jt_ * 16 + m) * 64 + ((c0_ + arot) & 63)]; \
        }

    LOADB_(0);                                // prologue hides under staging + barrier
    LOADB_(1);
    LOADB_(2);

    #pragma unroll
    for (int it = 0; it < 9; ++it) {          // stage all 9 taps, 16B/lane coalesced
        int e = it * 512 + tid;
        *(bf16x8*)&sW[e * 8] = *(const bf16x8*)(Wh + e * 8);
    }
    __syncthreads();

    f32x4 acc[4][2];                          // [jt][xt], 32 AGPR
    #pragma unroll
    for (int i = 0; i < 4; ++i)
        #pragma unroll
        for (int j = 0; j < 2; ++j)
            #pragma unroll
            for (int rr = 0; rr < 4; ++rr) acc[i][j][rr] = 0.f;

    LOADA_(0);

    #pragma unroll
    for (int k = 0; k < 18; ++k) {            // 18 clusters = 9 taps x 2 c0-halves
        if (k + 3 < 18) LOADB_(k + 3);        // issue 3 clusters ahead (WAR-pinned)
        if (k + 1 < 18) LOADA_(k + 1);        // LDS prefetch 1 cluster ahead
        #pragma unroll
        for (int jt = 0; jt < 4; ++jt)
            #pragma unroll
            for (int xt = 0; xt < 2; ++xt)
                acc[jt][xt] = __builtin_amdgcn_mfma_f32_16x16x32_bf16(
                    aFb[k & 1][jt], bFb[k & 3][xt], acc[jt][xt], 0, 0, 0);
    }
#undef LOADB_
#undef LOADA_

    #pragma unroll
    for (int xt = 0; xt < 2; ++xt) {
        int xx = xbase + xt * 16 + m;
        if (xx < W_) {
            #pragma unroll
            for (int jt = 0; jt < 4; ++jt)
                #pragma unroll
                for (int rr = 0; rr < 4; ++rr) {
                    int j = jt * 16 + q * 4 + rr;         // D: row = quad*4 + reg
                    int oc = j * HEADS_ + h;              // head interleave
                    out[(((size_t)b * C_ + oc) * H_ + yrow) * W_ + xx] = acc[jt][xt][rr];
                }
        }
    }
}

// ---------------- launch ----------------------------------------------------------------
extern "C" void kernel_launch(void* const* d_in, const int* in_sizes, int n_in,
                              void* d_out, int out_size, void* d_ws, size_t ws_size,
                              hipStream_t stream)
{
    const float* x     = (const float*)d_in[0];
    const float* gamma = (const float*)d_in[1];
    const float* beta  = (const float*)d_in[2];
    const float* mean  = (const float*)d_in[3];
    const float* var   = (const float*)d_in[4];
    const float* fc1   = (const float*)d_in[5];
    const float* fc2   = (const float*)d_in[6];
    const float* fc2b  = (const float*)d_in[7];
    const float* convw = (const float*)d_in[8];
    const int*   kptr  = (const int*)d_in[9];

    float* out   = (float*)d_out;
    float* lasso = out + (size_t)B_ * C_ * HW_;

    char* ws = (char*)d_ws;
    size_t off = 0;
    short* xc    = (short*)(ws + off); off += (size_t)HEADS_ * B_ * HW_ * 64 * 2;  // 25.7 MB
    off = (off + 255) & ~(size_t)255;
    float* xavg  = (float*)(ws + off); off += (size_t)B_ * C_ * 4;
    int*   aidx64= (int*)  (ws + off); off += (size_t)HEADS_ * B_ * 64 * 4;
    off = (off + 255) & ~(size_t)255;
    short* Wc    = (short*)(ws + off); off += (size_t)HEADS_ * B_ * 9 * CPER_ * 64 * 2; // 4.72 MB

    hipMemsetAsync(lasso, 0, 4, stream);

    k_pool<<<B_ * C_ / 4, 256, 0, stream>>>(x, gamma, beta, mean, var, xavg);
    k_se_wg<<<HEADS_ * B_, 256, 0, stream>>>(xavg, fc1, fc2, fc2b, kptr, convw,
                                             aidx64, lasso, Wc);
    k_bnc<<<dim3(H_, B_), 256, 0, stream>>>(x, gamma, beta, mean, var, aidx64, xc);
    k_conv<<<HEADS_ * B_ * 14, 512, 0, stream>>>(xc, Wc, out);
}

// Round 9
// 187.031 us; speedup vs baseline: 1.7374x; 1.0352x over previous
//
#include <hip/hip_runtime.h>
#include <hip/hip_bf16.h>
#include <math.h>

#define B_     16
#define C_     256
#define H_     56
#define W_     56
#define HEADS_ 4
#define CPER_  64
#define R_     16
#define HW_    (H_*W_)      // 3136
#define BN_EPS_ 1e-5f

typedef short bf16x8 __attribute__((ext_vector_type(8)));
typedef float f32x4  __attribute__((ext_vector_type(4)));

__device__ inline unsigned short f2bf(float f) {
    unsigned int u = __builtin_bit_cast(unsigned int, f);
    u += 0x7fffu + ((u >> 16) & 1u);          // RNE (finite inputs only)
    return (unsigned short)(u >> 16);
}

// ---------------- K0: BN+ReLU+mean per (b,c) plane, 4 planes/block, 4-deep MLP ---------
__global__ __launch_bounds__(256) void k_pool(
    const float* __restrict__ x,
    const float* __restrict__ gamma, const float* __restrict__ beta,
    const float* __restrict__ mean,  const float* __restrict__ var,
    float* __restrict__ xavg)
{
    int wv = threadIdx.x >> 6, ln = threadIdx.x & 63;
    int plane = blockIdx.x * 4 + wv;          // b*256 + c
    int c = plane & (C_ - 1);
    float s = gamma[c] * rsqrtf(var[c] + BN_EPS_);
    float t = fmaf(-mean[c], s, beta[c]);
    const float4* xp = (const float4*)(x + (size_t)plane * HW_);
    float s0 = 0.f, s1 = 0.f, s2 = 0.f, s3 = 0.f;
    #pragma unroll
    for (int i = 0; i < 3; ++i) {             // 784 = 12*64 + 16; 4 loads in flight
        float4 a = xp[ln + (i * 4 + 0) * 64];
        float4 b2 = xp[ln + (i * 4 + 1) * 64];
        float4 c2 = xp[ln + (i * 4 + 2) * 64];
        float4 d = xp[ln + (i * 4 + 3) * 64];
        s0 += fmaxf(fmaf(a.x, s, t), 0.f) + fmaxf(fmaf(a.y, s, t), 0.f)
            + fmaxf(fmaf(a.z, s, t), 0.f) + fmaxf(fmaf(a.w, s, t), 0.f);
        s1 += fmaxf(fmaf(b2.x, s, t), 0.f) + fmaxf(fmaf(b2.y, s, t), 0.f)
            + fmaxf(fmaf(b2.z, s, t), 0.f) + fmaxf(fmaf(b2.w, s, t), 0.f);
        s2 += fmaxf(fmaf(c2.x, s, t), 0.f) + fmaxf(fmaf(c2.y, s, t), 0.f)
            + fmaxf(fmaf(c2.z, s, t), 0.f) + fmaxf(fmaf(c2.w, s, t), 0.f);
        s3 += fmaxf(fmaf(d.x, s, t), 0.f) + fmaxf(fmaf(d.y, s, t), 0.f)
            + fmaxf(fmaf(d.z, s, t), 0.f) + fmaxf(fmaf(d.w, s, t), 0.f);
    }
    if (ln < 16) {
        float4 e = xp[768 + ln];
        s0 += fmaxf(fmaf(e.x, s, t), 0.f) + fmaxf(fmaf(e.y, s, t), 0.f)
            + fmaxf(fmaf(e.z, s, t), 0.f) + fmaxf(fmaf(e.w, s, t), 0.f);
    }
    float sum = (s0 + s1) + (s2 + s3);
    for (int off = 32; off; off >>= 1) sum += __shfl_down(sum, off, 64);
    if (ln == 0) xavg[plane] = sum * (1.f / HW_);
}

// ---------------- K2: SE gate + threshold + lasso + weight gather (j-sliced, grid.y=4) -
// SE recomputed redundantly per j-slice block. R8 bug fixed: compaction is now a
// DETERMINISTIC ballot/prefix rank (ascending channel order) -- identical list in every
// block regardless of scheduling (the atomicAdd version gave each block a different
// permutation, desyncing Wc slots from xc slots).
__global__ __launch_bounds__(256) void k_se_wg(
    const float* __restrict__ xavg,
    const float* __restrict__ fc1, const float* __restrict__ fc2,
    const float* __restrict__ fc2b, const int* __restrict__ kptr,
    const float* __restrict__ convw,
    int* __restrict__ aidx64, float* __restrict__ lasso,
    short* __restrict__ Wc)
{
    int hb = blockIdx.x;              // h*B + b
    int j0 = blockIdx.y * 16;         // this block's j-slice
    int h = hb / B_, b = hb - h * B_;
    int tid = threadIdx.x;            // = channel c

    __shared__ float sav[C_], sy1[R_], smask[C_], sred[4], sthr;
    __shared__ int s_ord[C_];
    __shared__ unsigned long long sbal[4];
    __shared__ int s_act[64];
    __shared__ float s_mv[64];
    __shared__ short sO[9 * 1024];    // 18 KB staged weight slice

    sav[tid] = xavg[b * C_ + tid];
    __syncthreads();

    if (tid < R_) {
        const float* w = fc1 + (size_t)(h * R_ + tid) * C_;
        float acc = 0.f;
        for (int c2 = 0; c2 < C_; ++c2) acc = fmaf(sav[c2], w[c2], acc);
        sy1[tid] = fmaxf(acc, 0.f);
    }
    __syncthreads();

    const float* w2 = fc2 + (size_t)(h * C_ + tid) * R_;
    float acc = fc2b[h * C_ + tid];
    for (int r = 0; r < R_; ++r) acc = fmaf(sy1[r], w2[r], acc);
    float m = fmaxf(acc, 0.f);
    smask[tid] = m;
    __syncthreads();

    int lane = tid & 63, wv = tid >> 6;
    float ls = m;
    for (int off = 32; off > 0; off >>= 1) ls += __shfl_down(ls, off, 64);
    if (lane == 0) sred[wv] = ls;

    int cl = 0, ce = 0;
    for (int j = 0; j < C_; ++j) {
        float vj = smask[j];
        cl += (vj < m);
        ce += (vj == m);
    }
    if (tid == 0) sthr = -1e30f;
    __syncthreads();
    int k = kptr[0];
    if (k > 0 && cl <= k - 1 && (k - 1) < cl + ce) sthr = m;
    __syncthreads();

    float thr = sthr;
    float mc = (m <= thr) ? 0.f : m;

    // deterministic order-preserving compaction (ascending channel)
    bool active = (mc != 0.f);
    unsigned long long bal = __ballot(active);
    if (lane == 0) sbal[wv] = bal;
    __syncthreads();
    int base = 0, total = 0;
    #pragma unroll
    for (int w = 0; w < 4; ++w) {
        int pc = __popcll(sbal[w]);
        if (w < wv) base += pc;
        total += pc;
    }
    if (active)
        s_ord[base + __popcll(bal & ((1ull << lane) - 1ull))] = tid;
    __syncthreads();

    if (tid < 64) {
        int a = (tid < total) ? s_ord[tid] : 0;  // zero-padded (padded weights are 0)
        s_act[tid] = a;
        s_mv[tid]  = (tid < total) ? smask[a] : 0.f;
        if (blockIdx.y == 0) aidx64[hb * 64 + tid] = a;
    }
    if (tid == 0 && blockIdx.y == 0)
        atomicAdd(lasso, (sred[0] + sred[1] + sred[2] + sred[3]) * (1.f / (B_ * C_)));
    __syncthreads();

    // ---- weight gather for j in [j0, j0+16): 36B granules, rotated stage, coalesced out
    const float* wsrc = convw + (size_t)h * CPER_ * C_ * 9;
    for (int it = 0; it < 4; ++it) {
        int e = it * 256 + tid;               // e < 1024 = 16j x 64cp
        int cp = e & 63, jj = e >> 6;
        int j = j0 + jj;
        const float* wp = wsrc + ((size_t)j * C_ + s_act[cp]) * 9;
        float mv = s_mv[cp];
        int slot = (cp + 8 * (j & 7)) & 63;   // pre-rotate for k_conv LDS bank spread
        #pragma unroll
        for (int t = 0; t < 9; ++t)
            sO[t * 1024 + jj * 64 + slot] = (short)f2bf(wp[t] * mv);
    }
    __syncthreads();
    short* wdst = Wc + (size_t)hb * 9 * 4096 + j0 * 64;
    for (int it = 0; it < 5; ++it) {          // 1152 bf16x8 vecs
        int v = it * 256 + tid;
        if (v < 1152) {
            int t = v >> 7, r8 = v & 127;     // 128 vec8 per tap slice
            *(bf16x8*)&wdst[t * 4096 + r8 * 8] = *(const bf16x8*)&sO[t * 1024 + r8 * 8];
        }
    }
}

// ---------------- K1: BN+ReLU+bf16 DIRECT channel compaction -> xc[hb][px][64] ---------
__global__ __launch_bounds__(256) void k_bnc(
    const float* __restrict__ x,
    const float* __restrict__ gamma, const float* __restrict__ beta,
    const float* __restrict__ mean,  const float* __restrict__ var,
    const int* __restrict__ aidx64, short* __restrict__ xc)
{
    int y = blockIdx.x, b = blockIdx.y;
    int tid = threadIdx.x;                    // tid = h*64 + cp
    int h = tid >> 6;
    __shared__ __align__(16) unsigned short T[W_ * 256];   // [px][h*64+cp], 28.7 KB

    int c = aidx64[(h * B_ + b) * 64 + (tid & 63)];        // padded slots -> c=0 (weights are 0)
    float s = gamma[c] * rsqrtf(var[c] + BN_EPS_);
    float t0 = fmaf(-mean[c], s, beta[c]);
    const float* xrow = x + ((size_t)(b * C_ + c)) * HW_ + y * W_;
    #pragma unroll
    for (int f = 0; f < 14; ++f) {
        float4 v = *(const float4*)(xrow + f * 4);
        int px = f * 4;
        T[(px + 0) * 256 + tid] = f2bf(fmaxf(fmaf(v.x, s, t0), 0.f));
        T[(px + 1) * 256 + tid] = f2bf(fmaxf(fmaf(v.y, s, t0), 0.f));
        T[(px + 2) * 256 + tid] = f2bf(fmaxf(fmaf(v.z, s, t0), 0.f));
        T[(px + 3) * 256 + tid] = f2bf(fmaxf(fmaf(v.w, s, t0), 0.f));
    }
    __syncthreads();

    const uint2* Ts = (const uint2*)T;        // 64 uint2 per pixel row
    uint2* ob = (uint2*)xc;
    #pragma unroll
    for (int it = 0; it < 14; ++it) {
        int e = it * 256 + tid;               // e < 3584 = 56px * 64 uint2
        int px = e >> 6, col4 = e & 63;       // col4 = (h*64+cp)/4
        int hh = col4 >> 4, cp4 = col4 & 15;
        uint2 v = Ts[px * 64 + col4];
        ob[((size_t)(hh * B_ + b) * HW_ + (size_t)y * W_ + px) * 16 + cp4] = v;
    }
}

// ---------------- K3: implicit-GEMM conv, HALF-GRID (hb 0-3 or 4-7 per XCD window) -----
// Split into two independent dispatches so k_conv's 5 bench iterations stop saturating
// the rocprof top-5 and the other kernels finally surface. Halves are read-shared /
// write-disjoint; same XCD swizzle per hb. Per-wave code = R7 (64ch x 32px tile).
__global__ __launch_bounds__(512, 2) void k_conv(
    const short* __restrict__ xc, const short* __restrict__ Wc,
    float* __restrict__ out, int hbhalf)
{
    int g = blockIdx.x;
    int vx = g & 7, r = g >> 3;               // r in [0,56)
    int b14 = r / 14;                         // 0..3
    int sub = r - b14 * 14;                   // 0..13
    int hb = vx * 8 + hbhalf * 4 + b14;
    int band = sub >> 1, xh = sub & 1;
    int h = hb >> 4, b = hb & 15;
    int tid = threadIdx.x, lane = tid & 63, wv = tid >> 6;   // wv 0..7 = row
    int m = lane & 15, q = lane >> 4;
    int yrow = band * 8 + wv;
    int xbase = xh * 32;
    int arot = q * 8 + 8 * (m & 7);           // A-frag slot rotation (add c0, &63)

    __shared__ short sW[9 * 4096];            // 73.7 KB, all taps

    const short* Wh = Wc + (size_t)hb * 9 * 4096;
    const short* xb = xc + (size_t)hb * HW_ * 64 + q * 8;   // q*8 folded into base

    bf16x8 bFb[4][2];                         // B rotating buffer, 3-deep (32 VGPR)
    bf16x8 aFb[2][4];                         // A rotating buffer (32 VGPR)

#define LOADB_(kk) { \
        const int t_ = (kk) >> 1, c0_ = ((kk) & 1) * 32; \
        const int dy_ = t_ / 3 - 1, dx_ = t_ % 3 - 1; \
        int gy_ = yrow + dy_; \
        bool ok_ = (unsigned)gy_ < (unsigned)H_; \
        _Pragma("unroll") \
        for (int xt_ = 0; xt_ < 2; ++xt_) { \
            int gx_ = xbase + xt_ * 16 + m + dx_; \
            bf16x8 v_ = {0, 0, 0, 0, 0, 0, 0, 0}; \
            if (ok_ && (unsigned)gx_ < (unsigned)W_) \
                v_ = *(const bf16x8*)(xb + ((size_t)(gy_ * W_ + gx_)) * 64 + c0_); \
            bFb[(kk) & 3][xt_] = v_; \
        } }

#define LOADA_(kk) { \
        const int t_ = (kk) >> 1, c0_ = ((kk) & 1) * 32; \
        const short* sWc_ = sW + t_ * 4096; \
        _Pragma("unroll") \
        for (int jt_ = 0; jt_ < 4; ++jt_) \
            aFb[(kk) & 1][jt_] = *(const bf16x8*)&sWc_[(jt_ * 16 + m) * 64 + ((c0_ + arot) & 63)]; \
        }

    LOADB_(0);                                // prologue hides under staging + barrier
    LOADB_(1);
    LOADB_(2);

    #pragma unroll
    for (int it = 0; it < 9; ++it) {          // stage all 9 taps, 16B/lane coalesced
        int e = it * 512 + tid;
        *(bf16x8*)&sW[e * 8] = *(const bf16x8*)(Wh + e * 8);
    }
    __syncthreads();

    f32x4 acc[4][2];                          // [jt][xt], 32 AGPR
    #pragma unroll
    for (int i = 0; i < 4; ++i)
        #pragma unroll
        for (int j = 0; j < 2; ++j)
            #pragma unroll
            for (int rr = 0; rr < 4; ++rr) acc[i][j][rr] = 0.f;

    LOADA_(0);

    #pragma unroll
    for (int k = 0; k < 18; ++k) {            // 18 clusters = 9 taps x 2 c0-halves
        if (k + 3 < 18) LOADB_(k + 3);        // issue 3 clusters ahead (WAR-pinned)
        if (k + 1 < 18) LOADA_(k + 1);        // LDS prefetch 1 cluster ahead
        #pragma unroll
        for (int jt = 0; jt < 4; ++jt)
            #pragma unroll
            for (int xt = 0; xt < 2; ++xt)
                acc[jt][xt] = __builtin_amdgcn_mfma_f32_16x16x32_bf16(
                    aFb[k & 1][jt], bFb[k & 3][xt], acc[jt][xt], 0, 0, 0);
    }
#undef LOADB_
#undef LOADA_

    #pragma unroll
    for (int xt = 0; xt < 2; ++xt) {
        int xx = xbase + xt * 16 + m;
        if (xx < W_) {
            #pragma unroll
            for (int jt = 0; jt < 4; ++jt)
                #pragma unroll
                for (int rr = 0; rr < 4; ++rr) {
                    int j = jt * 16 + q * 4 + rr;         // D: row = quad*4 + reg
                    int oc = j * HEADS_ + h;              // head interleave
                    out[(((size_t)b * C_ + oc) * H_ + yrow) * W_ + xx] = acc[jt][xt][rr];
                }
        }
    }
}

// ---------------- launch ----------------------------------------------------------------
extern "C" void kernel_launch(void* const* d_in, const int* in_sizes, int n_in,
                              void* d_out, int out_size, void* d_ws, size_t ws_size,
                              hipStream_t stream)
{
    const float* x     = (const float*)d_in[0];
    const float* gamma = (const float*)d_in[1];
    const float* beta  = (const float*)d_in[2];
    const float* mean  = (const float*)d_in[3];
    const float* var   = (const float*)d_in[4];
    const float* fc1   = (const float*)d_in[5];
    const float* fc2   = (const float*)d_in[6];
    const float* fc2b  = (const float*)d_in[7];
    const float* convw = (const float*)d_in[8];
    const int*   kptr  = (const int*)d_in[9];

    float* out   = (float*)d_out;
    float* lasso = out + (size_t)B_ * C_ * HW_;

    char* ws = (char*)d_ws;
    size_t off = 0;
    short* xc    = (short*)(ws + off); off += (size_t)HEADS_ * B_ * HW_ * 64 * 2;  // 25.7 MB
    off = (off + 255) & ~(size_t)255;
    float* xavg  = (float*)(ws + off); off += (size_t)B_ * C_ * 4;
    int*   aidx64= (int*)  (ws + off); off += (size_t)HEADS_ * B_ * 64 * 4;
    off = (off + 255) & ~(size_t)255;
    short* Wc    = (short*)(ws + off); off += (size_t)HEADS_ * B_ * 9 * CPER_ * 64 * 2; // 4.72 MB

    hipMemsetAsync(lasso, 0, 4, stream);

    k_pool<<<B_ * C_ / 4, 256, 0, stream>>>(x, gamma, beta, mean, var, xavg);
    k_se_wg<<<dim3(HEADS_ * B_, 4), 256, 0, stream>>>(xavg, fc1, fc2, fc2b, kptr, convw,
                                                      aidx64, lasso, Wc);
    k_bnc<<<dim3(H_, B_), 256, 0, stream>>>(x, gamma, beta, mean, var, aidx64, xc);
    k_conv<<<448, 512, 0, stream>>>(xc, Wc, out, 0);
    k_conv<<<448, 512, 0, stream>>>(xc, Wc, out, 1);
}

// Round 10
// 181.375 us; speedup vs baseline: 1.7916x; 1.0312x over previous
//
#include <hip/hip_runtime.h>
#include <hip/hip_bf16.h>
#include <math.h>

#define B_     16
#define C_     256
#define H_     56
#define W_     56
#define HEADS_ 4
#define CPER_  64
#define R_     16
#define HW_    (H_*W_)      // 3136
#define BN_EPS_ 1e-5f

typedef short bf16x8 __attribute__((ext_vector_type(8)));
typedef float f32x4  __attribute__((ext_vector_type(4)));

__device__ inline unsigned short f2bf(float f) {
    unsigned int u = __builtin_bit_cast(unsigned int, f);
    u += 0x7fffu + ((u >> 16) & 1u);          // RNE (finite inputs only)
    return (unsigned short)(u >> 16);
}

// ---------------- K0: BN+ReLU+mean per (b,c) plane, 4 planes/block, 4-deep MLP ---------
__global__ __launch_bounds__(256) void k_pool(
    const float* __restrict__ x,
    const float* __restrict__ gamma, const float* __restrict__ beta,
    const float* __restrict__ mean,  const float* __restrict__ var,
    float* __restrict__ xavg)
{
    int wv = threadIdx.x >> 6, ln = threadIdx.x & 63;
    int plane = blockIdx.x * 4 + wv;          // b*256 + c
    int c = plane & (C_ - 1);
    float s = gamma[c] * rsqrtf(var[c] + BN_EPS_);
    float t = fmaf(-mean[c], s, beta[c]);
    const float4* xp = (const float4*)(x + (size_t)plane * HW_);
    float s0 = 0.f, s1 = 0.f, s2 = 0.f, s3 = 0.f;
    #pragma unroll
    for (int i = 0; i < 3; ++i) {             // 784 = 12*64 + 16; 4 loads in flight
        float4 a = xp[ln + (i * 4 + 0) * 64];
        float4 b2 = xp[ln + (i * 4 + 1) * 64];
        float4 c2 = xp[ln + (i * 4 + 2) * 64];
        float4 d = xp[ln + (i * 4 + 3) * 64];
        s0 += fmaxf(fmaf(a.x, s, t), 0.f) + fmaxf(fmaf(a.y, s, t), 0.f)
            + fmaxf(fmaf(a.z, s, t), 0.f) + fmaxf(fmaf(a.w, s, t), 0.f);
        s1 += fmaxf(fmaf(b2.x, s, t), 0.f) + fmaxf(fmaf(b2.y, s, t), 0.f)
            + fmaxf(fmaf(b2.z, s, t), 0.f) + fmaxf(fmaf(b2.w, s, t), 0.f);
        s2 += fmaxf(fmaf(c2.x, s, t), 0.f) + fmaxf(fmaf(c2.y, s, t), 0.f)
            + fmaxf(fmaf(c2.z, s, t), 0.f) + fmaxf(fmaf(c2.w, s, t), 0.f);
        s3 += fmaxf(fmaf(d.x, s, t), 0.f) + fmaxf(fmaf(d.y, s, t), 0.f)
            + fmaxf(fmaf(d.z, s, t), 0.f) + fmaxf(fmaf(d.w, s, t), 0.f);
    }
    if (ln < 16) {
        float4 e = xp[768 + ln];
        s0 += fmaxf(fmaf(e.x, s, t), 0.f) + fmaxf(fmaf(e.y, s, t), 0.f)
            + fmaxf(fmaf(e.z, s, t), 0.f) + fmaxf(fmaf(e.w, s, t), 0.f);
    }
    float sum = (s0 + s1) + (s2 + s3);
    for (int off = 32; off; off >>= 1) sum += __shfl_down(sum, off, 64);
    if (ln == 0) xavg[plane] = sum * (1.f / HW_);
}

// ---------------- K2: SE gate + threshold + lasso + weight gather (j-sliced, grid.y=4) -
// Deterministic ballot/prefix compaction (ascending channel) -- identical list in every
// redundant block regardless of scheduling.
__global__ __launch_bounds__(256) void k_se_wg(
    const float* __restrict__ xavg,
    const float* __restrict__ fc1, const float* __restrict__ fc2,
    const float* __restrict__ fc2b, const int* __restrict__ kptr,
    const float* __restrict__ convw,
    int* __restrict__ aidx64, float* __restrict__ lasso,
    short* __restrict__ Wc)
{
    int hb = blockIdx.x;              // h*B + b
    int j0 = blockIdx.y * 16;         // this block's j-slice
    int h = hb / B_, b = hb - h * B_;
    int tid = threadIdx.x;            // = channel c

    __shared__ float sav[C_], sy1[R_], smask[C_], sred[4], sthr;
    __shared__ int s_ord[C_];
    __shared__ unsigned long long sbal[4];
    __shared__ int s_act[64];
    __shared__ float s_mv[64];
    __shared__ short sO[9 * 1024];    // 18 KB staged weight slice

    sav[tid] = xavg[b * C_ + tid];
    __syncthreads();

    if (tid < R_) {
        const float* w = fc1 + (size_t)(h * R_ + tid) * C_;
        float acc = 0.f;
        for (int c2 = 0; c2 < C_; ++c2) acc = fmaf(sav[c2], w[c2], acc);
        sy1[tid] = fmaxf(acc, 0.f);
    }
    __syncthreads();

    const float* w2 = fc2 + (size_t)(h * C_ + tid) * R_;
    float acc = fc2b[h * C_ + tid];
    for (int r = 0; r < R_; ++r) acc = fmaf(sy1[r], w2[r], acc);
    float m = fmaxf(acc, 0.f);
    smask[tid] = m;
    __syncthreads();

    int lane = tid & 63, wv = tid >> 6;
    float ls = m;
    for (int off = 32; off > 0; off >>= 1) ls += __shfl_down(ls, off, 64);
    if (lane == 0) sred[wv] = ls;

    int cl = 0, ce = 0;
    for (int j = 0; j < C_; ++j) {
        float vj = smask[j];
        cl += (vj < m);
        ce += (vj == m);
    }
    if (tid == 0) sthr = -1e30f;
    __syncthreads();
    int k = kptr[0];
    if (k > 0 && cl <= k - 1 && (k - 1) < cl + ce) sthr = m;
    __syncthreads();

    float thr = sthr;
    float mc = (m <= thr) ? 0.f : m;

    // deterministic order-preserving compaction (ascending channel)
    bool active = (mc != 0.f);
    unsigned long long bal = __ballot(active);
    if (lane == 0) sbal[wv] = bal;
    __syncthreads();
    int base = 0, total = 0;
    #pragma unroll
    for (int w = 0; w < 4; ++w) {
        int pc = __popcll(sbal[w]);
        if (w < wv) base += pc;
        total += pc;
    }
    if (active)
        s_ord[base + __popcll(bal & ((1ull << lane) - 1ull))] = tid;
    __syncthreads();

    if (tid < 64) {
        int a = (tid < total) ? s_ord[tid] : 0;  // zero-padded (padded weights are 0)
        s_act[tid] = a;
        s_mv[tid]  = (tid < total) ? smask[a] : 0.f;
        if (blockIdx.y == 0) aidx64[hb * 64 + tid] = a;
    }
    if (tid == 0 && blockIdx.y == 0)
        atomicAdd(lasso, (sred[0] + sred[1] + sred[2] + sred[3]) * (1.f / (B_ * C_)));
    __syncthreads();

    // ---- weight gather for j in [j0, j0+16): 36B granules, rotated stage, coalesced out
    const float* wsrc = convw + (size_t)h * CPER_ * C_ * 9;
    for (int it = 0; it < 4; ++it) {
        int e = it * 256 + tid;               // e < 1024 = 16j x 64cp
        int cp = e & 63, jj = e >> 6;
        int j = j0 + jj;
        const float* wp = wsrc + ((size_t)j * C_ + s_act[cp]) * 9;
        float mv = s_mv[cp];
        int slot = (cp + 8 * (j & 7)) & 63;   // pre-rotate for k_conv LDS bank spread
        #pragma unroll
        for (int t = 0; t < 9; ++t)
            sO[t * 1024 + jj * 64 + slot] = (short)f2bf(wp[t] * mv);
    }
    __syncthreads();
    short* wdst = Wc + (size_t)hb * 9 * 4096 + j0 * 64;
    for (int it = 0; it < 5; ++it) {          // 1152 bf16x8 vecs
        int v = it * 256 + tid;
        if (v < 1152) {
            int t = v >> 7, r8 = v & 127;     // 128 vec8 per tap slice
            *(bf16x8*)&wdst[t * 4096 + r8 * 8] = *(const bf16x8*)&sO[t * 1024 + r8 * 8];
        }
    }
}

// ---------------- K1: BN+ReLU+bf16 + per-head compaction, COALESCED reads --------------
// R1's "active-only read" was a false economy: it read 4x64=256 channel-rows SCATTERED
// (16B/lane, 64 cache lines per instr). Reading ALL 256 channels coalesced (14
// consecutive lanes stream one channel row = 224B segments) is the same byte count at
// full burst efficiency; the per-head compaction happens in LDS (T padded to 258).
__global__ __launch_bounds__(256) void k_bnc(
    const float* __restrict__ x,
    const float* __restrict__ gamma, const float* __restrict__ beta,
    const float* __restrict__ mean,  const float* __restrict__ var,
    const int* __restrict__ aidx64, short* __restrict__ xc)
{
    int y = blockIdx.x, b = blockIdx.y;
    int tid = threadIdx.x;
    __shared__ unsigned short T[W_ * 258];    // [px][c], +2 pad breaks stride-256 conflicts
    __shared__ float ss[C_], st[C_];
    __shared__ short sact[256];               // [h][64]

    {
        float s = gamma[tid] * rsqrtf(var[tid] + BN_EPS_);
        ss[tid] = s;
        st[tid] = fmaf(-mean[tid], s, beta[tid]);
        int h = tid >> 6, cp = tid & 63;
        sact[tid] = (short)aidx64[(h * B_ + b) * 64 + cp];
    }
    __syncthreads();

    const float* xrow = x + (size_t)b * C_ * HW_ + y * W_;
    for (int i = tid; i < C_ * 14; i += 256) {    // 14 float4 per channel row, coalesced
        int c = i / 14, f = i - c * 14;
        float4 v = *(const float4*)(xrow + (size_t)c * HW_ + f * 4);
        float s = ss[c], t = st[c];
        int xb = f * 4;
        T[(xb + 0) * 258 + c] = f2bf(fmaxf(fmaf(v.x, s, t), 0.f));
        T[(xb + 1) * 258 + c] = f2bf(fmaxf(fmaf(v.y, s, t), 0.f));
        T[(xb + 2) * 258 + c] = f2bf(fmaxf(fmaf(v.z, s, t), 0.f));
        T[(xb + 3) * 258 + c] = f2bf(fmaxf(fmaf(v.w, s, t), 0.f));
    }
    __syncthreads();

    unsigned int* ob = (unsigned int*)xc;
    #pragma unroll
    for (int h = 0; h < HEADS_; ++h) {
        size_t obase = ((size_t)(h * B_ + b) * HW_ + (size_t)y * W_) * 32;
        for (int i = tid; i < W_ * 32; i += 256) {    // 56 px x 32 dwords, 7 iters
            int px = i >> 5, d = i & 31;
            unsigned int lo = T[px * 258 + sact[h * 64 + 2 * d]];
            unsigned int hi = T[px * 258 + sact[h * 64 + 2 * d + 1]];
            ob[obase + i] = lo | (hi << 16);
        }
    }
}

// ---------------- K3: implicit-GEMM conv -- R4-exact (best measured: 44.3us single) ----
// Single dispatch, 896 blocks (the R8/R9 half-split serialized on-stream and cost +4us).
// 64ch x 64px wave tile, manual pipeline: bFb[3] (2-deep global B), aFb[2] (LDS A),
// fully unrolled compile-time indices. One barrier total.
__global__ __launch_bounds__(256, 2) void k_conv(
    const short* __restrict__ xc, const short* __restrict__ Wc,
    float* __restrict__ out)
{
    int g = blockIdx.x;
    int vx = g & 7, r = g >> 3;               // XCD-local hb window (Wc/xc L2-resident)
    int hb = vx * 8 + r / 14;
    int band = r - (r / 14) * 14;
    int h = hb >> 4, b = hb & 15;
    int tid = threadIdx.x, lane = tid & 63, wv = tid >> 6;
    int m = lane & 15, q = lane >> 4;
    int yrow = band * 4 + wv;
    int arot = q * 8 + 8 * (m & 7);           // A-frag slot rotation (add c0, &63)

    __shared__ short sW[9 * 4096];            // 73.7 KB, all taps

    const short* Wh = Wc + (size_t)hb * 9 * 4096;
    const short* xb = xc + (size_t)hb * HW_ * 64 + q * 8;   // q*8 folded into base

    bf16x8 bFb[3][4];                         // B rotating buffer (48 VGPR)
    bf16x8 aFb[2][4];                         // A rotating buffer (32 VGPR)

#define LOADB_(kk) { \
        const int t_ = (kk) >> 1, c0_ = ((kk) & 1) * 32; \
        const int dy_ = t_ / 3 - 1, dx_ = t_ % 3 - 1; \
        int gy_ = yrow + dy_; \
        bool ok_ = (unsigned)gy_ < (unsigned)H_; \
        _Pragma("unroll") \
        for (int xt_ = 0; xt_ < 4; ++xt_) { \
            int gx_ = xt_ * 16 + m + dx_; \
            bf16x8 v_ = {0, 0, 0, 0, 0, 0, 0, 0}; \
            if (ok_ && (unsigned)gx_ < (unsigned)W_) \
                v_ = *(const bf16x8*)(xb + ((size_t)(gy_ * W_ + gx_)) * 64 + c0_); \
            bFb[(kk) % 3][xt_] = v_; \
        } }

#define LOADA_(kk) { \
        const int t_ = (kk) >> 1, c0_ = ((kk) & 1) * 32; \
        const short* sWc_ = sW + t_ * 4096; \
        _Pragma("unroll") \
        for (int jt_ = 0; jt_ < 4; ++jt_) \
            aFb[(kk) % 2][jt_] = *(const bf16x8*)&sWc_[(jt_ * 16 + m) * 64 + ((c0_ + arot) & 63)]; \
        }

    LOADB_(0);                                // hide under staging + barrier
    LOADB_(1);

    #pragma unroll
    for (int it = 0; it < 18; ++it) {         // stage all 9 taps, 16B/lane coalesced
        int e = it * 256 + tid;
        *(bf16x8*)&sW[e * 8] = *(const bf16x8*)(Wh + e * 8);
    }
    __syncthreads();

    f32x4 acc[4][4];                          // [jt][xt], 64 AGPR
    #pragma unroll
    for (int i = 0; i < 4; ++i)
        #pragma unroll
        for (int j = 0; j < 4; ++j)
            #pragma unroll
            for (int rr = 0; rr < 4; ++rr) acc[i][j][rr] = 0.f;

    LOADA_(0);

    #pragma unroll
    for (int k = 0; k < 18; ++k) {            // 18 clusters = 9 taps x 2 c0-halves
        if (k + 2 < 18) LOADB_(k + 2);        // issue 2 clusters ahead (WAR-pinned)
        if (k + 1 < 18) LOADA_(k + 1);        // LDS prefetch 1 cluster ahead
        #pragma unroll
        for (int jt = 0; jt < 4; ++jt)
            #pragma unroll
            for (int xt = 0; xt < 4; ++xt)
                acc[jt][xt] = __builtin_amdgcn_mfma_f32_16x16x32_bf16(
                    aFb[k % 2][jt], bFb[k % 3][xt], acc[jt][xt], 0, 0, 0);
    }
#undef LOADB_
#undef LOADA_

    #pragma unroll
    for (int xt = 0; xt < 4; ++xt) {
        int xx = xt * 16 + m;
        if (xx < W_) {
            #pragma unroll
            for (int jt = 0; jt < 4; ++jt)
                #pragma unroll
                for (int rr = 0; rr < 4; ++rr) {
                    int j = jt * 16 + q * 4 + rr;         // D: row = quad*4 + reg
                    int oc = j * HEADS_ + h;              // head interleave
                    out[(((size_t)b * C_ + oc) * H_ + yrow) * W_ + xx] = acc[jt][xt][rr];
                }
        }
    }
}

// ---------------- launch ----------------------------------------------------------------
extern "C" void kernel_launch(void* const* d_in, const int* in_sizes, int n_in,
                              void* d_out, int out_size, void* d_ws, size_t ws_size,
                              hipStream_t stream)
{
    const float* x     = (const float*)d_in[0];
    const float* gamma = (const float*)d_in[1];
    const float* beta  = (const float*)d_in[2];
    const float* mean  = (const float*)d_in[3];
    const float* var   = (const float*)d_in[4];
    const float* fc1   = (const float*)d_in[5];
    const float* fc2   = (const float*)d_in[6];
    const float* fc2b  = (const float*)d_in[7];
    const float* convw = (const float*)d_in[8];
    const int*   kptr  = (const int*)d_in[9];

    float* out   = (float*)d_out;
    float* lasso = out + (size_t)B_ * C_ * HW_;

    char* ws = (char*)d_ws;
    size_t off = 0;
    short* xc    = (short*)(ws + off); off += (size_t)HEADS_ * B_ * HW_ * 64 * 2;  // 25.7 MB
    off = (off + 255) & ~(size_t)255;
    float* xavg  = (float*)(ws + off); off += (size_t)B_ * C_ * 4;
    int*   aidx64= (int*)  (ws + off); off += (size_t)HEADS_ * B_ * 64 * 4;
    off = (off + 255) & ~(size_t)255;
    short* Wc    = (short*)(ws + off); off += (size_t)HEADS_ * B_ * 9 * CPER_ * 64 * 2; // 4.72 MB

    hipMemsetAsync(lasso, 0, 4, stream);

    k_pool<<<B_ * C_ / 4, 256, 0, stream>>>(x, gamma, beta, mean, var, xavg);
    k_se_wg<<<dim3(HEADS_ * B_, 4), 256, 0, stream>>>(xavg, fc1, fc2, fc2b, kptr, convw,
                                                      aidx64, lasso, Wc);
    k_bnc<<<dim3(H_, B_), 256, 0, stream>>>(x, gamma, beta, mean, var, aidx64, xc);
    k_conv<<<HEADS_ * B_ * (H_ / 4), 256, 0, stream>>>(xc, Wc, out);
}